// Round 3
// baseline (4701.787 us; speedup 1.0000x reference)
//
#include <hip/hip_runtime.h>
#include <math.h>

#define NR 8192
#define DDIM 128

static constexpr float LOG_AB  = -9.010913347279288f; // -ln(8192)
static constexpr float INV_EPS = 20.0f;               // 1/0.05
static constexpr float DQX     = 20.0f / 65535.0f;    // dequant -> k*INV_EPS
static constexpr float DQK     = 1.0f / 65535.0f;     // dequant -> k

// ordered-uint transform: monotone float -> uint for atomicMax
__device__ inline unsigned f2key(float f) {
    unsigned b = __float_as_uint(f);
    return (b & 0x80000000u) ? ~b : (b | 0x80000000u);
}
__device__ inline float key2f(unsigned k) {
    return __uint_as_float((k & 0x80000000u) ? (k & 0x7fffffffu) : ~k);
}

// scal_u layout (uint32 index): [0]=kmax bits; doubles [1..3]*: scal_d[1]=kxx,[2]=kyy,[3]=S
// [16..47] = maxlu[it] keys ; [48..79] = maxlv[it] keys (maxlv[0] = key(0.0))
__global__ void init_k(unsigned* scal_u) { scal_u[48] = 0x80000000u; }

// ---------------- row squared-norms: 64 lanes per row ----------------
__global__ __launch_bounds__(256) void rownorm_k(const float* __restrict__ X,
                                                 float* __restrict__ nrm) {
    const int lane = threadIdx.x & 63;
    const int w    = threadIdx.x >> 6;
    const int row  = blockIdx.x * 4 + w;
    const float2 v = *reinterpret_cast<const float2*>(&X[(size_t)row * DDIM + lane * 2]);
    float s = v.x * v.x + v.y * v.y;
#pragma unroll
    for (int off = 32; off; off >>= 1) s += __shfl_xor(s, off);
    if (lane == 0) nrm[row] = s;
}

// ---------------- GEMM + multi-scale RBF ----------------
// MODE 0: full 64x64 grid, store quantized K + global max (atomicMax on scal_u[0]).
// MODE 1: triangular 2080-block grid, sum only (double off-diagonal blocks).
template <int MODE>
__global__ __launch_bounds__(256) void gemm_rbf_k(const float* __restrict__ A,
                                                  const float* __restrict__ B,
                                                  const float* __restrict__ na,
                                                  const float* __restrict__ nb,
                                                  unsigned short* __restrict__ K16,
                                                  unsigned* __restrict__ maxbits,
                                                  double* __restrict__ sumout) {
    int bm, bn;
    if (MODE == 0) {
        bm = blockIdx.x; bn = blockIdx.y;
    } else {
        const int lin = blockIdx.x;  // 0..2079 triangular (bm<=bn)
        int i = (int)((129.0f - sqrtf(16641.0f - 8.0f * (float)lin)) * 0.5f);
        while (i * 64 - i * (i - 1) / 2 > lin) --i;
        while ((i + 1) * 64 - (i + 1) * i / 2 <= lin) ++i;
        bm = i;
        bn = i + (lin - (i * 64 - i * (i - 1) / 2));
    }
    __shared__ float As[32 * 128];   // k-major [k][m]
    __shared__ float Bs[32 * 128];   // k-major [k][n]
    const int t   = threadIdx.x;
    const int row = t & 127;
    const int kh  = t >> 7;          // 0/1
    const float* Arow = &A[(size_t)(bm * 128 + row) * DDIM];
    const float* Brow = &B[(size_t)(bn * 128 + row) * DDIM];
    const int tx = t & 15, ty = t >> 4;

    float acc[8][8];
#pragma unroll
    for (int i = 0; i < 8; ++i)
#pragma unroll
        for (int j = 0; j < 8; ++j) acc[i][j] = 0.f;

    for (int kc = 0; kc < 4; ++kc) {
        __syncthreads();
#pragma unroll
        for (int p = 0; p < 4; ++p) {
            const int k4 = kh + 2 * p;  // 0..7 within chunk
            const float4 va = *reinterpret_cast<const float4*>(&Arow[kc * 32 + k4 * 4]);
            As[(4 * k4 + 0) * 128 + row] = va.x;
            As[(4 * k4 + 1) * 128 + row] = va.y;
            As[(4 * k4 + 2) * 128 + row] = va.z;
            As[(4 * k4 + 3) * 128 + row] = va.w;
            const float4 vb = *reinterpret_cast<const float4*>(&Brow[kc * 32 + k4 * 4]);
            Bs[(4 * k4 + 0) * 128 + row] = vb.x;
            Bs[(4 * k4 + 1) * 128 + row] = vb.y;
            Bs[(4 * k4 + 2) * 128 + row] = vb.z;
            Bs[(4 * k4 + 3) * 128 + row] = vb.w;
        }
        __syncthreads();
#pragma unroll 8
        for (int k = 0; k < 32; ++k) {
            const float4 a0 = *reinterpret_cast<const float4*>(&As[k * 128 + ty * 4]);
            const float4 a1 = *reinterpret_cast<const float4*>(&As[k * 128 + 64 + ty * 4]);
            const float4 b0 = *reinterpret_cast<const float4*>(&Bs[k * 128 + tx * 4]);
            const float4 b1 = *reinterpret_cast<const float4*>(&Bs[k * 128 + 64 + tx * 4]);
            const float a[8] = {a0.x, a0.y, a0.z, a0.w, a1.x, a1.y, a1.z, a1.w};
            const float b[8] = {b0.x, b0.y, b0.z, b0.w, b1.x, b1.y, b1.z, b1.w};
#pragma unroll
            for (int i = 0; i < 8; ++i)
#pragma unroll
                for (int j = 0; j < 8; ++j) acc[i][j] = fmaf(a[i], b[j], acc[i][j]);
        }
    }

    const int m0 = bm * 128, n0 = bn * 128;
    float nbv[8];
#pragma unroll
    for (int j = 0; j < 8; ++j) nbv[j] = nb[n0 + tx * 4 + (j & 3) + (j >> 2) * 64];

    float  lmax = 0.f;
    double lsum = 0.0;
#pragma unroll
    for (int i = 0; i < 8; ++i) {
        const int   mi  = m0 + ty * 4 + (i & 3) + (i >> 2) * 64;
        const float nav = na[mi];
        float kv[8];
#pragma unroll
        for (int j = 0; j < 8; ++j) {
            float d2 = fmaf(-2.f, acc[i][j], nav + nbv[j]);
            d2 = fmaxf(d2, 0.f);
            kv[j] = 0.2f * (__expf(d2 * -0.5f) + __expf(d2 * -0.125f) +
                            __expf(d2 * -0.03125f) + __expf(d2 * -0.0078125f) +
                            __expf(d2 * -0.001953125f));
        }
        if (MODE == 0) {
            ushort4 o0, o1;
            o0.x = (unsigned short)__float2uint_rn(kv[0] * 65535.f);
            o0.y = (unsigned short)__float2uint_rn(kv[1] * 65535.f);
            o0.z = (unsigned short)__float2uint_rn(kv[2] * 65535.f);
            o0.w = (unsigned short)__float2uint_rn(kv[3] * 65535.f);
            o1.x = (unsigned short)__float2uint_rn(kv[4] * 65535.f);
            o1.y = (unsigned short)__float2uint_rn(kv[5] * 65535.f);
            o1.z = (unsigned short)__float2uint_rn(kv[6] * 65535.f);
            o1.w = (unsigned short)__float2uint_rn(kv[7] * 65535.f);
            *reinterpret_cast<ushort4*>(&K16[(size_t)mi * NR + n0 + tx * 4])      = o0;
            *reinterpret_cast<ushort4*>(&K16[(size_t)mi * NR + n0 + 64 + tx * 4]) = o1;
#pragma unroll
            for (int j = 0; j < 8; ++j) lmax = fmaxf(lmax, kv[j]);
        } else {
#pragma unroll
            for (int j = 0; j < 8; ++j) lsum += (double)kv[j];
        }
    }
    if (MODE == 0) {
#pragma unroll
        for (int off = 32; off; off >>= 1) lmax = fmaxf(lmax, __shfl_xor(lmax, off));
        if ((t & 63) == 0) atomicMax(maxbits, __float_as_uint(lmax));  // kv >= 0: bit order == float order
    } else {
        if (bn > bm) lsum *= 2.0;
#pragma unroll
        for (int off = 32; off; off >>= 1) lsum += __shfl_xor(lsum, off);
        if ((t & 63) == 0) atomicAdd(sumout, lsum);
    }
}

// ---------------- Sinkhorn row pass: one block per row, fixed-shift LSE ----------------
__global__ __launch_bounds__(256) void sink_row_k(const unsigned short* __restrict__ K16,
                                                  const float* __restrict__ log_v,
                                                  float* __restrict__ log_u,
                                                  unsigned* __restrict__ scal_u,
                                                  int it) {
    __shared__ float red[4];
    const int t = threadIdx.x;
    const size_t i = blockIdx.x;
    const float kmax  = __uint_as_float(scal_u[0]);
    const float maxlv = key2f(scal_u[48 + it]);
    const float off   = fmaf(-kmax, INV_EPS, -maxlv);  // bias - C_row
    const uint4*  Kr = reinterpret_cast<const uint4*>(K16 + i * NR);
    const float4* Lv = reinterpret_cast<const float4*>(log_v);
    float s = 0.f;
#pragma unroll
    for (int p = 0; p < 4; ++p) {
        const int g = t + p * 256;
        const uint4 w = Kr[g];
        const float4 lv0 = Lv[2 * g];
        const float4 lv1 = Lv[2 * g + 1];
        const unsigned wd[4] = {w.x, w.y, w.z, w.w};
        const float lvv[8] = {lv0.x, lv0.y, lv0.z, lv0.w, lv1.x, lv1.y, lv1.z, lv1.w};
#pragma unroll
        for (int e = 0; e < 4; ++e) {
            s += __expf(fmaf((float)(wd[e] & 0xFFFFu), DQX, lvv[2 * e]     + off));
            s += __expf(fmaf((float)(wd[e] >> 16),     DQX, lvv[2 * e + 1] + off));
        }
    }
#pragma unroll
    for (int o = 32; o; o >>= 1) s += __shfl_xor(s, o);
    if ((t & 63) == 0) red[t >> 6] = s;
    __syncthreads();
    if (t == 0) {
        const float stot = (red[0] + red[1]) + (red[2] + red[3]);
        const float lu = LOG_AB - (maxlv + logf(stot));
        log_u[i] = lu;
        atomicMax(&scal_u[16 + it], f2key(lu));
    }
}

// ---------------- Sinkhorn column pass: partial sums over 32-row chunks ----------------
__global__ __launch_bounds__(256) void sink_colp_k(const unsigned short* __restrict__ K16,
                                                   const float* __restrict__ log_u,
                                                   float* __restrict__ ps,
                                                   const unsigned* __restrict__ scal_u,
                                                   int it) {
    const int t  = threadIdx.x;
    const int cg = blockIdx.x * 256 + t;  // uint4 col group, 0..1023 (cols 8cg..8cg+7)
    const int rc = blockIdx.y;            // row chunk, 0..255 (32 rows each)
    const float kmax  = __uint_as_float(scal_u[0]);
    const float maxlu = key2f(scal_u[16 + it]);
    const float off   = fmaf(-kmax, INV_EPS, -maxlu);  // bias - C_col
    const uint4* base = reinterpret_cast<const uint4*>(K16) + (size_t)rc * 32 * 1024 + cg;
    const float* lu = log_u + rc * 32;
    float s8[8];
#pragma unroll
    for (int e = 0; e < 8; ++e) s8[e] = 0.f;
#pragma unroll 4
    for (int r = 0; r < 32; ++r) {
        const uint4 w = base[(size_t)r * 1024];
        const float lup = lu[r] + off;
        const unsigned wd[4] = {w.x, w.y, w.z, w.w};
#pragma unroll
        for (int e = 0; e < 4; ++e) {
            s8[2 * e]     += __expf(fmaf((float)(wd[e] & 0xFFFFu), DQX, lup));
            s8[2 * e + 1] += __expf(fmaf((float)(wd[e] >> 16),     DQX, lup));
        }
    }
    float4* pv = reinterpret_cast<float4*>(ps + (size_t)rc * NR + cg * 8);
    pv[0] = {s8[0], s8[1], s8[2], s8[3]};
    pv[1] = {s8[4], s8[5], s8[6], s8[7]};
}

__global__ __launch_bounds__(256) void sink_combine_k(const float* __restrict__ ps,
                                                      float* __restrict__ log_v,
                                                      unsigned* __restrict__ scal_u,
                                                      int it) {
    const int j = blockIdx.x * 256 + threadIdx.x;
    const float maxlu = key2f(scal_u[16 + it]);
    float s = 0.f;
#pragma unroll 8
    for (int c = 0; c < 256; ++c) s += ps[(size_t)c * NR + j];
    const float lv = LOG_AB - (maxlu + logf(s));
    log_v[j] = lv;
    float m = lv;
#pragma unroll
    for (int o = 32; o; o >>= 1) m = fmaxf(m, __shfl_xor(m, o));
    if ((threadIdx.x & 63) == 0) atomicMax(&scal_u[48 + it + 1], f2key(m));
}

// ---------------- final sum(Gamma * Kxy) ----------------
__global__ __launch_bounds__(256) void gamma_sum_k(const unsigned short* __restrict__ K16,
                                                   const float* __restrict__ log_u,
                                                   const float* __restrict__ log_v,
                                                   const unsigned* __restrict__ scal_u,
                                                   double* __restrict__ S) {
    const int t  = threadIdx.x;
    const int cg = blockIdx.x * 256 + t;
    const int rc = blockIdx.y;  // 0..255, 32 rows each
    const float bias = -__uint_as_float(scal_u[0]) * INV_EPS;
    const float4 lv0 = reinterpret_cast<const float4*>(log_v)[2 * cg];
    const float4 lv1 = reinterpret_cast<const float4*>(log_v)[2 * cg + 1];
    const float lvv[8] = {lv0.x, lv0.y, lv0.z, lv0.w, lv1.x, lv1.y, lv1.z, lv1.w};
    const uint4* base = reinterpret_cast<const uint4*>(K16) + (size_t)rc * 32 * 1024 + cg;
    const float* lu = log_u + rc * 32;
    double acc = 0.0;
#pragma unroll 4
    for (int r = 0; r < 32; ++r) {
        const uint4 w = base[(size_t)r * 1024];
        const float lur = lu[r] + bias;
        const unsigned wd[4] = {w.x, w.y, w.z, w.w};
        float rs = 0.f;
#pragma unroll
        for (int e = 0; e < 4; ++e) {
            const float q0 = (float)(wd[e] & 0xFFFFu);
            const float q1 = (float)(wd[e] >> 16);
            rs += __expf(fmaf(q0, DQX, lur + lvv[2 * e]))     * (q0 * DQK);
            rs += __expf(fmaf(q1, DQX, lur + lvv[2 * e + 1])) * (q1 * DQK);
        }
        acc += (double)rs;
    }
#pragma unroll
    for (int o = 32; o; o >>= 1) acc += __shfl_xor(acc, o);
    if ((t & 63) == 0) atomicAdd(S, acc);
}

__global__ void finalize_k(const double* __restrict__ scal, float* __restrict__ out) {
    const double inv = 1.0 / (8192.0 * 8192.0);
    out[0] = (float)(scal[1] * inv + scal[2] * inv - 2.0 * scal[3]);
}

extern "C" void kernel_launch(void* const* d_in, const int* in_sizes, int n_in,
                              void* d_out, int out_size, void* d_ws, size_t ws_size,
                              hipStream_t stream) {
    const float* X = (const float*)d_in[0];
    const float* Y = (const float*)d_in[1];

    // ---- workspace layout ----
    char* ws = (char*)d_ws;
    unsigned short* K16 = (unsigned short*)ws;            // 134217728 B
    float* nx    = (float*)(ws + 134217728);              // 32 KB each
    float* ny    = nx + NR;
    float* log_u = ny + NR;
    float* log_v = log_u + NR;
    char*  scal  = (char*)(log_v + NR);                   // 512 B (aligned)
    unsigned* scal_u = (unsigned*)scal;
    double*   scal_d = (double*)scal;                     // [1]=kxx, [2]=kyy, [3]=S
    float* ps = (float*)(scal + 512);                     // 256*8192*4 = 8 MB
    const size_t needed = 134217728 + 4 * (size_t)NR * 4 + 512 + 256 * (size_t)NR * 4;
    if (ws_size < needed) return;  // clean absmax failure instead of a GPU fault

    // zero log_u, log_v, scalar block (ws is poisoned 0xAA before every call)
    hipMemsetAsync(log_u, 0, 2 * NR * sizeof(float) + 512, stream);
    init_k<<<1, 1, 0, stream>>>(scal_u);  // maxlv[0] = key(0.0f)

    rownorm_k<<<NR / 4, 256, 0, stream>>>(X, nx);
    rownorm_k<<<NR / 4, 256, 0, stream>>>(Y, ny);

    gemm_rbf_k<0><<<dim3(64, 64), 256, 0, stream>>>(X, Y, nx, ny, K16, scal_u, nullptr);
    gemm_rbf_k<1><<<2080, 256, 0, stream>>>(X, X, nx, nx, nullptr, nullptr, scal_d + 1);
    gemm_rbf_k<1><<<2080, 256, 0, stream>>>(Y, Y, ny, ny, nullptr, nullptr, scal_d + 2);

    for (int it = 0; it < 30; ++it) {
        sink_row_k<<<NR, 256, 0, stream>>>(K16, log_v, log_u, scal_u, it);
        sink_colp_k<<<dim3(4, 256), 256, 0, stream>>>(K16, log_u, ps, scal_u, it);
        sink_combine_k<<<32, 256, 0, stream>>>(ps, log_v, scal_u, it);
    }

    gamma_sum_k<<<dim3(4, 256), 256, 0, stream>>>(K16, log_u, log_v, scal_u, scal_d + 3);
    finalize_k<<<1, 1, 0, stream>>>(scal_d, (float*)d_out);
}

// Round 4
// 1898.920 us; speedup vs baseline: 2.4760x; 2.4760x over previous
//
#include <hip/hip_runtime.h>
#include <math.h>

#define NR 8192
#define DDIM 128

static constexpr float LOG_AB  = -9.010913347279288f; // -ln(8192)
static constexpr float INV_EPS = 20.0f;               // 1/0.05
static constexpr float DQX8    = 20.0f / 255.0f;      // dequant -> k*INV_EPS
static constexpr float DQK8    = 1.0f / 255.0f;       // dequant -> k

// ordered-uint transform: monotone float -> uint for atomicMax
__device__ inline unsigned f2key(float f) {
    unsigned b = __float_as_uint(f);
    return (b & 0x80000000u) ? ~b : (b | 0x80000000u);
}
__device__ inline float key2f(unsigned k) {
    return __uint_as_float((k & 0x80000000u) ? (k & 0x7fffffffu) : ~k);
}

// scal_u layout (uint32 idx): [0]=kmax bits; scal_d[1]=kxx,[2]=kyy,[3]=S (doubles)
// [16..47] = maxlu[it] keys ; [48..79] = maxlv[it] keys (maxlv[0] = key(0.0))
__global__ void init_k(unsigned* scal_u) { scal_u[48] = 0x80000000u; }

// ---------------- row squared-norms ----------------
__global__ __launch_bounds__(256) void rownorm_k(const float* __restrict__ X,
                                                 float* __restrict__ nrm) {
    const int lane = threadIdx.x & 63;
    const int w    = threadIdx.x >> 6;
    const int row  = blockIdx.x * 4 + w;
    const float2 v = *reinterpret_cast<const float2*>(&X[(size_t)row * DDIM + lane * 2]);
    float s = v.x * v.x + v.y * v.y;
#pragma unroll
    for (int off = 32; off; off >>= 1) s += __shfl_xor(s, off);
    if (lane == 0) nrm[row] = s;
}

// ---------------- GEMM + multi-scale RBF ----------------
// MODE 0: full 64x64 grid, store uint8-quantized K + global kmax.
// MODE 1: triangular 2080-block grid, sum only (double off-diagonal blocks).
template <int MODE>
__global__ __launch_bounds__(256) void gemm_rbf_k(const float* __restrict__ A,
                                                  const float* __restrict__ B,
                                                  const float* __restrict__ na,
                                                  const float* __restrict__ nb,
                                                  unsigned char* __restrict__ K8,
                                                  unsigned* __restrict__ maxbits,
                                                  double* __restrict__ sumout) {
    int bm, bn;
    if (MODE == 0) {
        bm = blockIdx.x; bn = blockIdx.y;
    } else {
        const int lin = blockIdx.x;  // 0..2079 triangular (bm<=bn)
        int i = (int)((129.0f - sqrtf(16641.0f - 8.0f * (float)lin)) * 0.5f);
        while (i * 64 - i * (i - 1) / 2 > lin) --i;
        while ((i + 1) * 64 - (i + 1) * i / 2 <= lin) ++i;
        bm = i;
        bn = i + (lin - (i * 64 - i * (i - 1) / 2));
    }
    __shared__ float As[32 * 128];   // k-major [k][m]
    __shared__ float Bs[32 * 128];   // k-major [k][n]
    __shared__ float redmax[4];
    const int t   = threadIdx.x;
    const int row = t & 127;
    const int kh  = t >> 7;          // 0/1
    const float* Arow = &A[(size_t)(bm * 128 + row) * DDIM];
    const float* Brow = &B[(size_t)(bn * 128 + row) * DDIM];
    const int tx = t & 15, ty = t >> 4;

    float acc[8][8];
#pragma unroll
    for (int i = 0; i < 8; ++i)
#pragma unroll
        for (int j = 0; j < 8; ++j) acc[i][j] = 0.f;

    for (int kc = 0; kc < 4; ++kc) {
        __syncthreads();
#pragma unroll
        for (int p = 0; p < 4; ++p) {
            const int k4 = kh + 2 * p;  // 0..7 within chunk
            const float4 va = *reinterpret_cast<const float4*>(&Arow[kc * 32 + k4 * 4]);
            As[(4 * k4 + 0) * 128 + row] = va.x;
            As[(4 * k4 + 1) * 128 + row] = va.y;
            As[(4 * k4 + 2) * 128 + row] = va.z;
            As[(4 * k4 + 3) * 128 + row] = va.w;
            const float4 vb = *reinterpret_cast<const float4*>(&Brow[kc * 32 + k4 * 4]);
            Bs[(4 * k4 + 0) * 128 + row] = vb.x;
            Bs[(4 * k4 + 1) * 128 + row] = vb.y;
            Bs[(4 * k4 + 2) * 128 + row] = vb.z;
            Bs[(4 * k4 + 3) * 128 + row] = vb.w;
        }
        __syncthreads();
#pragma unroll 8
        for (int k = 0; k < 32; ++k) {
            const float4 a0 = *reinterpret_cast<const float4*>(&As[k * 128 + ty * 4]);
            const float4 a1 = *reinterpret_cast<const float4*>(&As[k * 128 + 64 + ty * 4]);
            const float4 b0 = *reinterpret_cast<const float4*>(&Bs[k * 128 + tx * 4]);
            const float4 b1 = *reinterpret_cast<const float4*>(&Bs[k * 128 + 64 + tx * 4]);
            const float a[8] = {a0.x, a0.y, a0.z, a0.w, a1.x, a1.y, a1.z, a1.w};
            const float b[8] = {b0.x, b0.y, b0.z, b0.w, b1.x, b1.y, b1.z, b1.w};
#pragma unroll
            for (int i = 0; i < 8; ++i)
#pragma unroll
                for (int j = 0; j < 8; ++j) acc[i][j] = fmaf(a[i], b[j], acc[i][j]);
        }
    }

    const int m0 = bm * 128, n0 = bn * 128;
    float nbv[8];
#pragma unroll
    for (int j = 0; j < 8; ++j) nbv[j] = nb[n0 + tx * 4 + (j & 3) + (j >> 2) * 64];

    float  lmax = 0.f;
    double lsum = 0.0;
#pragma unroll
    for (int i = 0; i < 8; ++i) {
        const int   mi  = m0 + ty * 4 + (i & 3) + (i >> 2) * 64;
        const float nav = na[mi];
        float kv[8];
#pragma unroll
        for (int j = 0; j < 8; ++j) {
            float d2 = fmaf(-2.f, acc[i][j], nav + nbv[j]);
            d2 = fmaxf(d2, 0.f);
            kv[j] = 0.2f * (__expf(d2 * -0.5f) + __expf(d2 * -0.125f) +
                            __expf(d2 * -0.03125f) + __expf(d2 * -0.0078125f) +
                            __expf(d2 * -0.001953125f));
        }
        if (MODE == 0) {
            uchar4 o0, o1;
            o0.x = (unsigned char)__float2uint_rn(kv[0] * 255.f);
            o0.y = (unsigned char)__float2uint_rn(kv[1] * 255.f);
            o0.z = (unsigned char)__float2uint_rn(kv[2] * 255.f);
            o0.w = (unsigned char)__float2uint_rn(kv[3] * 255.f);
            o1.x = (unsigned char)__float2uint_rn(kv[4] * 255.f);
            o1.y = (unsigned char)__float2uint_rn(kv[5] * 255.f);
            o1.z = (unsigned char)__float2uint_rn(kv[6] * 255.f);
            o1.w = (unsigned char)__float2uint_rn(kv[7] * 255.f);
            *reinterpret_cast<uchar4*>(&K8[(size_t)mi * NR + n0 + tx * 4])      = o0;
            *reinterpret_cast<uchar4*>(&K8[(size_t)mi * NR + n0 + 64 + tx * 4]) = o1;
#pragma unroll
            for (int j = 0; j < 8; ++j) lmax = fmaxf(lmax, kv[j]);
        } else {
#pragma unroll
            for (int j = 0; j < 8; ++j) lsum += (double)kv[j];
        }
    }
    if (MODE == 0) {
#pragma unroll
        for (int off = 32; off; off >>= 1) lmax = fmaxf(lmax, __shfl_xor(lmax, off));
        if ((t & 63) == 0) redmax[t >> 6] = lmax;
        __syncthreads();
        if (t == 0) {
            lmax = fmaxf(fmaxf(redmax[0], redmax[1]), fmaxf(redmax[2], redmax[3]));
            atomicMax(maxbits, __float_as_uint(lmax));  // kv >= 0: bit order == float order
        }
    } else {
        if (bn > bm) lsum *= 2.0;
#pragma unroll
        for (int off = 32; off; off >>= 1) lsum += __shfl_xor(lsum, off);
        if ((t & 63) == 0) atomicAdd(sumout, lsum);
    }
}

// ---------------- Sinkhorn row pass: 8 rows per block, fixed-shift LSE ----------------
__global__ __launch_bounds__(256) void sink_row_k(const unsigned char* __restrict__ K8,
                                                  const float* __restrict__ log_v,
                                                  float* __restrict__ log_u,
                                                  unsigned* __restrict__ scal_u,
                                                  int it) {
    __shared__ float red[4][8];
    const int t  = threadIdx.x;
    const int r0 = blockIdx.x * 8;
    const float kmax  = __uint_as_float(scal_u[0]);
    const float maxlv = key2f(scal_u[48 + it]);
    const float off   = fmaf(-kmax, INV_EPS, -maxlv);
    const float4* Lv = reinterpret_cast<const float4*>(log_v);
    float s[8];
#pragma unroll
    for (int r = 0; r < 8; ++r) s[r] = 0.f;
#pragma unroll
    for (int p = 0; p < 4; ++p) {
        const int g = t + p * 256;  // uint2 col-group: cols 8g..8g+7
        const float4 lv0 = Lv[2 * g];
        const float4 lv1 = Lv[2 * g + 1];
        float lvv[8] = {lv0.x + off, lv0.y + off, lv0.z + off, lv0.w + off,
                        lv1.x + off, lv1.y + off, lv1.z + off, lv1.w + off};
        const uint2* col = reinterpret_cast<const uint2*>(K8 + (size_t)r0 * NR) + g;
#pragma unroll
        for (int r = 0; r < 8; ++r) {
            const uint2 w = col[(size_t)r * 1024];
            const unsigned a = w.x, b = w.y;
            s[r] += __expf(fmaf((float)(a & 255u),         DQX8, lvv[0]))
                  + __expf(fmaf((float)((a >> 8) & 255u),  DQX8, lvv[1]))
                  + __expf(fmaf((float)((a >> 16) & 255u), DQX8, lvv[2]))
                  + __expf(fmaf((float)(a >> 24),          DQX8, lvv[3]))
                  + __expf(fmaf((float)(b & 255u),         DQX8, lvv[4]))
                  + __expf(fmaf((float)((b >> 8) & 255u),  DQX8, lvv[5]))
                  + __expf(fmaf((float)((b >> 16) & 255u), DQX8, lvv[6]))
                  + __expf(fmaf((float)(b >> 24),          DQX8, lvv[7]));
        }
    }
    const int lane = t & 63, w = t >> 6;
#pragma unroll
    for (int r = 0; r < 8; ++r) {
        float v = s[r];
#pragma unroll
        for (int o = 32; o; o >>= 1) v += __shfl_xor(v, o);
        if (lane == 0) red[w][r] = v;
    }
    __syncthreads();
    if (t < 8) {
        const float stot = (red[0][t] + red[1][t]) + (red[2][t] + red[3][t]);
        float lu = LOG_AB - (maxlv + logf(stot));
        log_u[r0 + t] = lu;
#pragma unroll
        for (int o = 4; o; o >>= 1) lu = fmaxf(lu, __shfl_xor(lu, o));
        if (t == 0) atomicMax(&scal_u[16 + it], f2key(lu));  // 1 atomic per block
    }
}

// ---------------- Sinkhorn column pass: partial sums over 64-row chunks ----------------
__global__ __launch_bounds__(256) void sink_colp_k(const unsigned char* __restrict__ K8,
                                                   const float* __restrict__ log_u,
                                                   float* __restrict__ ps,
                                                   const unsigned* __restrict__ scal_u,
                                                   int it) {
    const int t  = threadIdx.x;
    const int cg = blockIdx.x * 256 + t;  // uint2 col-group: cols 8cg..8cg+7
    const int rc = blockIdx.y;            // row chunk, 0..127 (64 rows each)
    const float kmax  = __uint_as_float(scal_u[0]);
    const float maxlu = key2f(scal_u[16 + it]);
    const float off   = fmaf(-kmax, INV_EPS, -maxlu);
    const uint2* base = reinterpret_cast<const uint2*>(K8) + (size_t)rc * 64 * 1024 + cg;
    const float* lu = log_u + rc * 64;
    float s8[8];
#pragma unroll
    for (int e = 0; e < 8; ++e) s8[e] = 0.f;
#pragma unroll 4
    for (int r = 0; r < 64; ++r) {
        const uint2 w = base[(size_t)r * 1024];
        const float lup = lu[r] + off;
        const unsigned a = w.x, b = w.y;
        s8[0] += __expf(fmaf((float)(a & 255u),         DQX8, lup));
        s8[1] += __expf(fmaf((float)((a >> 8) & 255u),  DQX8, lup));
        s8[2] += __expf(fmaf((float)((a >> 16) & 255u), DQX8, lup));
        s8[3] += __expf(fmaf((float)(a >> 24),          DQX8, lup));
        s8[4] += __expf(fmaf((float)(b & 255u),         DQX8, lup));
        s8[5] += __expf(fmaf((float)((b >> 8) & 255u),  DQX8, lup));
        s8[6] += __expf(fmaf((float)((b >> 16) & 255u), DQX8, lup));
        s8[7] += __expf(fmaf((float)(b >> 24),          DQX8, lup));
    }
    float4* pv = reinterpret_cast<float4*>(ps + (size_t)rc * NR + cg * 8);
    pv[0] = {s8[0], s8[1], s8[2], s8[3]};
    pv[1] = {s8[4], s8[5], s8[6], s8[7]};
}

// combine: block = 64 cols x 4 chunk-groups; coalesced reads + LDS reduce
__global__ __launch_bounds__(256) void sink_combine_k(const float* __restrict__ ps,
                                                      float* __restrict__ log_v,
                                                      unsigned* __restrict__ scal_u,
                                                      int it) {
    __shared__ float red[4][64];
    const int lane = threadIdx.x & 63;
    const int grp  = threadIdx.x >> 6;
    const int col  = blockIdx.x * 64 + lane;
    float s = 0.f;
#pragma unroll 8
    for (int c = grp * 32; c < grp * 32 + 32; ++c) s += ps[(size_t)c * NR + col];
    red[grp][lane] = s;
    __syncthreads();
    if (grp == 0) {
        const float stot = (red[0][lane] + red[1][lane]) + (red[2][lane] + red[3][lane]);
        const float maxlu = key2f(scal_u[16 + it]);
        const float lv = LOG_AB - (maxlu + logf(stot));
        log_v[col] = lv;
        float m = lv;
#pragma unroll
        for (int o = 32; o; o >>= 1) m = fmaxf(m, __shfl_xor(m, o));
        if (lane == 0) atomicMax(&scal_u[48 + it + 1], f2key(m));
    }
}

// ---------------- final sum(Gamma * Kxy) ----------------
__global__ __launch_bounds__(256) void gamma_sum_k(const unsigned char* __restrict__ K8,
                                                   const float* __restrict__ log_u,
                                                   const float* __restrict__ log_v,
                                                   const unsigned* __restrict__ scal_u,
                                                   double* __restrict__ S) {
    const int t  = threadIdx.x;
    const int cg = blockIdx.x * 256 + t;  // uint2 col-group: cols 8cg..8cg+7
    const int rc = blockIdx.y;            // 0..255, 32 rows each
    const float bias = -__uint_as_float(scal_u[0]) * INV_EPS;
    const float4 lv0 = reinterpret_cast<const float4*>(log_v)[2 * cg];
    const float4 lv1 = reinterpret_cast<const float4*>(log_v)[2 * cg + 1];
    const float lvv[8] = {lv0.x, lv0.y, lv0.z, lv0.w, lv1.x, lv1.y, lv1.z, lv1.w};
    const uint2* base = reinterpret_cast<const uint2*>(K8) + (size_t)rc * 32 * 1024 + cg;
    const float* lu = log_u + rc * 32;
    double acc = 0.0;
#pragma unroll 4
    for (int r = 0; r < 32; ++r) {
        const uint2 w = base[(size_t)r * 1024];
        const float lur = lu[r] + bias;
        const unsigned a = w.x, b = w.y;
        float rs = 0.f;
        {
            const float q0 = (float)(a & 255u),         q1 = (float)((a >> 8) & 255u);
            const float q2 = (float)((a >> 16) & 255u), q3 = (float)(a >> 24);
            rs += __expf(fmaf(q0, DQX8, lur + lvv[0])) * (q0 * DQK8);
            rs += __expf(fmaf(q1, DQX8, lur + lvv[1])) * (q1 * DQK8);
            rs += __expf(fmaf(q2, DQX8, lur + lvv[2])) * (q2 * DQK8);
            rs += __expf(fmaf(q3, DQX8, lur + lvv[3])) * (q3 * DQK8);
        }
        {
            const float q0 = (float)(b & 255u),         q1 = (float)((b >> 8) & 255u);
            const float q2 = (float)((b >> 16) & 255u), q3 = (float)(b >> 24);
            rs += __expf(fmaf(q0, DQX8, lur + lvv[4])) * (q0 * DQK8);
            rs += __expf(fmaf(q1, DQX8, lur + lvv[5])) * (q1 * DQK8);
            rs += __expf(fmaf(q2, DQX8, lur + lvv[6])) * (q2 * DQK8);
            rs += __expf(fmaf(q3, DQX8, lur + lvv[7])) * (q3 * DQK8);
        }
        acc += (double)rs;
    }
#pragma unroll
    for (int o = 32; o; o >>= 1) acc += __shfl_xor(acc, o);
    if ((t & 63) == 0) atomicAdd(S, acc);
}

__global__ void finalize_k(const double* __restrict__ scal, float* __restrict__ out) {
    const double inv = 1.0 / (8192.0 * 8192.0);
    out[0] = (float)(scal[1] * inv + scal[2] * inv - 2.0 * scal[3]);
}

extern "C" void kernel_launch(void* const* d_in, const int* in_sizes, int n_in,
                              void* d_out, int out_size, void* d_ws, size_t ws_size,
                              hipStream_t stream) {
    const float* X = (const float*)d_in[0];
    const float* Y = (const float*)d_in[1];

    // ---- workspace layout ----
    char* ws = (char*)d_ws;
    unsigned char* K8 = (unsigned char*)ws;               // 67108864 B
    float* nx    = (float*)(ws + 67108864);               // 32 KB each
    float* ny    = nx + NR;
    float* log_u = ny + NR;
    float* log_v = log_u + NR;
    char*  scal  = (char*)(log_v + NR);                   // 512 B
    unsigned* scal_u = (unsigned*)scal;
    double*   scal_d = (double*)scal;                     // [1]=kxx, [2]=kyy, [3]=S
    float* ps = (float*)(scal + 512);                     // 128*8192*4 = 4 MB
    const size_t needed = 67108864 + 4 * (size_t)NR * 4 + 512 + 128 * (size_t)NR * 4;
    if (ws_size < needed) return;  // clean absmax failure instead of a GPU fault

    // zero log_u, log_v, scalar block (ws is poisoned 0xAA before every call)
    hipMemsetAsync(log_u, 0, 2 * NR * sizeof(float) + 512, stream);
    init_k<<<1, 1, 0, stream>>>(scal_u);  // maxlv[0] = key(0.0f)

    rownorm_k<<<NR / 4, 256, 0, stream>>>(X, nx);
    rownorm_k<<<NR / 4, 256, 0, stream>>>(Y, ny);

    gemm_rbf_k<0><<<dim3(64, 64), 256, 0, stream>>>(X, Y, nx, ny, K8, scal_u, nullptr);
    gemm_rbf_k<1><<<2080, 256, 0, stream>>>(X, X, nx, nx, nullptr, nullptr, scal_d + 1);
    gemm_rbf_k<1><<<2080, 256, 0, stream>>>(Y, Y, ny, ny, nullptr, nullptr, scal_d + 2);

    for (int it = 0; it < 30; ++it) {
        sink_row_k<<<NR / 8, 256, 0, stream>>>(K8, log_v, log_u, scal_u, it);
        sink_colp_k<<<dim3(4, 128), 256, 0, stream>>>(K8, log_u, ps, scal_u, it);
        sink_combine_k<<<128, 256, 0, stream>>>(ps, log_v, scal_u, it);
    }

    gamma_sum_k<<<dim3(4, 256), 256, 0, stream>>>(K8, log_u, log_v, scal_u, scal_d + 3);
    finalize_k<<<1, 1, 0, stream>>>(scal_d, (float*)d_out);
}

// Round 5
// 1768.047 us; speedup vs baseline: 2.6593x; 1.0740x over previous
//
#include <hip/hip_runtime.h>
#include <math.h>

#define NR 8192
#define DDIM 128

static constexpr float LOG_AB2      = -13.0f;                 // -ln(8192)*log2e = -log2(8192)
static constexpr float INV_EPS      = 20.0f;                  // 1/0.05
static constexpr float L2E          = 1.4426950408889634f;
static constexpr float INV_EPS_L2E  = 28.853900817779268f;    // 20*log2e
static constexpr float C8           = 0.11315255222658537f;   // (20/255)*log2e
static constexpr float DQK8         = 1.0f / 255.0f;
// RBF scale constants in log2 domain: -log2e/(2 s^2)
static constexpr float E1 = -0.7213475204444817f;
static constexpr float E2 = -0.18033688011112043f;
static constexpr float E3 = -0.045084220027780107f;
static constexpr float E4 = -0.011271055006945027f;
static constexpr float E5 = -0.0028177637517362567f;

#if defined(__has_builtin)
#if __has_builtin(__builtin_amdgcn_exp2f)
#define EX2_IMPL(x) __builtin_amdgcn_exp2f(x)
#endif
#endif
#ifndef EX2_IMPL
extern "C" __device__ float __ocml_native_exp2_f32(float);
#define EX2_IMPL(x) __ocml_native_exp2_f32(x)
#endif
__device__ inline float ex2(float x) { return EX2_IMPL(x); }

// scal layout: scal_u[0] = kmax bits; scal_d[1]=kxx, [2]=kyy, [3]=S (doubles)

// ---------------- row squared-norms ----------------
__global__ __launch_bounds__(256) void rownorm_k(const float* __restrict__ X,
                                                 float* __restrict__ nrm) {
    const int lane = threadIdx.x & 63;
    const int w    = threadIdx.x >> 6;
    const int row  = blockIdx.x * 4 + w;
    const float2 v = *reinterpret_cast<const float2*>(&X[(size_t)row * DDIM + lane * 2]);
    float s = v.x * v.x + v.y * v.y;
#pragma unroll
    for (int off = 32; off; off >>= 1) s += __shfl_xor(s, off);
    if (lane == 0) nrm[row] = s;
}

// ---------------- GEMM + multi-scale RBF ----------------
// MODE 0: full 64x64 grid: A=X,B=Y, store uint8 K + global kmax.
// MODE 1: triangular 2080 x 2 grid: blockIdx.y selects X or Y; sum only.
template <int MODE>
__global__ __launch_bounds__(256) void gemm_rbf_k(const float* __restrict__ Xp,
                                                  const float* __restrict__ Yp,
                                                  const float* __restrict__ nxp,
                                                  const float* __restrict__ nyp,
                                                  unsigned char* __restrict__ K8,
                                                  unsigned* __restrict__ maxbits,
                                                  double* __restrict__ sums) {
    int bm, bn;
    const float *A, *B, *na, *nb;
    if (MODE == 0) {
        bm = blockIdx.x; bn = blockIdx.y;
        A = Xp; B = Yp; na = nxp; nb = nyp;
    } else {
        const int lin = blockIdx.x;  // 0..2079 triangular (bm<=bn)
        int i = (int)((129.0f - sqrtf(16641.0f - 8.0f * (float)lin)) * 0.5f);
        while (i * 64 - i * (i - 1) / 2 > lin) --i;
        while ((i + 1) * 64 - (i + 1) * i / 2 <= lin) ++i;
        bm = i;
        bn = i + (lin - (i * 64 - i * (i - 1) / 2));
        const int sel = blockIdx.y;
        A = B = sel ? Yp : Xp;
        na = nb = sel ? nyp : nxp;
    }
    __shared__ float As[32 * 128];   // k-major [k][m]
    __shared__ float Bs[32 * 128];   // k-major [k][n]
    __shared__ float redmax[4];
    const int t   = threadIdx.x;
    const int row = t & 127;
    const int kh  = t >> 7;          // 0/1
    const float* Arow = &A[(size_t)(bm * 128 + row) * DDIM];
    const float* Brow = &B[(size_t)(bn * 128 + row) * DDIM];
    const int tx = t & 15, ty = t >> 4;

    float acc[8][8];
#pragma unroll
    for (int i = 0; i < 8; ++i)
#pragma unroll
        for (int j = 0; j < 8; ++j) acc[i][j] = 0.f;

    for (int kc = 0; kc < 4; ++kc) {
        __syncthreads();
#pragma unroll
        for (int p = 0; p < 4; ++p) {
            const int k4 = kh + 2 * p;  // 0..7 within chunk
            const float4 va = *reinterpret_cast<const float4*>(&Arow[kc * 32 + k4 * 4]);
            As[(4 * k4 + 0) * 128 + row] = va.x;
            As[(4 * k4 + 1) * 128 + row] = va.y;
            As[(4 * k4 + 2) * 128 + row] = va.z;
            As[(4 * k4 + 3) * 128 + row] = va.w;
            const float4 vb = *reinterpret_cast<const float4*>(&Brow[kc * 32 + k4 * 4]);
            Bs[(4 * k4 + 0) * 128 + row] = vb.x;
            Bs[(4 * k4 + 1) * 128 + row] = vb.y;
            Bs[(4 * k4 + 2) * 128 + row] = vb.z;
            Bs[(4 * k4 + 3) * 128 + row] = vb.w;
        }
        __syncthreads();
#pragma unroll 8
        for (int k = 0; k < 32; ++k) {
            const float4 a0 = *reinterpret_cast<const float4*>(&As[k * 128 + ty * 4]);
            const float4 a1 = *reinterpret_cast<const float4*>(&As[k * 128 + 64 + ty * 4]);
            const float4 b0 = *reinterpret_cast<const float4*>(&Bs[k * 128 + tx * 4]);
            const float4 b1 = *reinterpret_cast<const float4*>(&Bs[k * 128 + 64 + tx * 4]);
            const float a[8] = {a0.x, a0.y, a0.z, a0.w, a1.x, a1.y, a1.z, a1.w};
            const float b[8] = {b0.x, b0.y, b0.z, b0.w, b1.x, b1.y, b1.z, b1.w};
#pragma unroll
            for (int i = 0; i < 8; ++i)
#pragma unroll
                for (int j = 0; j < 8; ++j) acc[i][j] = fmaf(a[i], b[j], acc[i][j]);
        }
    }

    const int m0 = bm * 128, n0 = bn * 128;
    float nbv[8];
#pragma unroll
    for (int j = 0; j < 8; ++j) nbv[j] = nb[n0 + tx * 4 + (j & 3) + (j >> 2) * 64];

    float  lmax = 0.f;
    double lsum = 0.0;
#pragma unroll
    for (int i = 0; i < 8; ++i) {
        const int   mi  = m0 + ty * 4 + (i & 3) + (i >> 2) * 64;
        const float nav = na[mi];
        float kv[8];
#pragma unroll
        for (int j = 0; j < 8; ++j) {
            float d2 = fmaf(-2.f, acc[i][j], nav + nbv[j]);
            d2 = fmaxf(d2, 0.f);
            kv[j] = 0.2f * (ex2(d2 * E1) + ex2(d2 * E2) + ex2(d2 * E3) +
                            ex2(d2 * E4) + ex2(d2 * E5));
        }
        if (MODE == 0) {
            uchar4 o0, o1;
            o0.x = (unsigned char)__float2uint_rn(kv[0] * 255.f);
            o0.y = (unsigned char)__float2uint_rn(kv[1] * 255.f);
            o0.z = (unsigned char)__float2uint_rn(kv[2] * 255.f);
            o0.w = (unsigned char)__float2uint_rn(kv[3] * 255.f);
            o1.x = (unsigned char)__float2uint_rn(kv[4] * 255.f);
            o1.y = (unsigned char)__float2uint_rn(kv[5] * 255.f);
            o1.z = (unsigned char)__float2uint_rn(kv[6] * 255.f);
            o1.w = (unsigned char)__float2uint_rn(kv[7] * 255.f);
            *reinterpret_cast<uchar4*>(&K8[(size_t)mi * NR + n0 + tx * 4])      = o0;
            *reinterpret_cast<uchar4*>(&K8[(size_t)mi * NR + n0 + 64 + tx * 4]) = o1;
#pragma unroll
            for (int j = 0; j < 8; ++j) lmax = fmaxf(lmax, kv[j]);
        } else {
#pragma unroll
            for (int j = 0; j < 8; ++j) lsum += (double)kv[j];
        }
    }
    if (MODE == 0) {
#pragma unroll
        for (int off = 32; off; off >>= 1) lmax = fmaxf(lmax, __shfl_xor(lmax, off));
        if ((t & 63) == 0) redmax[t >> 6] = lmax;
        __syncthreads();
        if (t == 0) {
            lmax = fmaxf(fmaxf(redmax[0], redmax[1]), fmaxf(redmax[2], redmax[3]));
            atomicMax(maxbits, __float_as_uint(lmax));  // kv >= 0: bit order == float order
        }
    } else {
        if (bn > bm) lsum *= 2.0;
#pragma unroll
        for (int off = 32; off; off >>= 1) lsum += __shfl_xor(lsum, off);
        if ((t & 63) == 0) atomicAdd(&sums[1 + blockIdx.y], lsum);
    }
}

// log_v initial state: log_v = 0  ->  stored lv_st = 0*L2E + off2 = -kmax*20*log2e
__global__ __launch_bounds__(256) void init_lv_k(float* __restrict__ log_v,
                                                 const unsigned* __restrict__ scal_u) {
    const float kmax = __uint_as_float(scal_u[0]);
    log_v[blockIdx.x * 256 + threadIdx.x] = -kmax * INV_EPS_L2E;
}

// ---------------- Sinkhorn row pass: 8 rows/block, log2-domain fixed shift ----------------
// lu_st[i] = LOG_AB2 - log2(sum_j exp2(q*C8 + lv_st[j])) + off2
__global__ __launch_bounds__(256) void sink_row_k(const unsigned char* __restrict__ K8,
                                                  const float* __restrict__ log_v,
                                                  float* __restrict__ log_u,
                                                  const unsigned* __restrict__ scal_u) {
    __shared__ float red[4][8];
    const int t  = threadIdx.x;
    const int r0 = blockIdx.x * 8;
    const float off2 = -__uint_as_float(scal_u[0]) * INV_EPS_L2E;
    const float4* Lv4 = reinterpret_cast<const float4*>(log_v);
    float s[8];
#pragma unroll
    for (int r = 0; r < 8; ++r) s[r] = 0.f;
#pragma unroll
    for (int p = 0; p < 2; ++p) {
        const int g = t + p * 256;  // uint4 group: cols 16g..16g+15
        const float4 l0 = Lv4[4 * g + 0];
        const float4 l1 = Lv4[4 * g + 1];
        const float4 l2 = Lv4[4 * g + 2];
        const float4 l3 = Lv4[4 * g + 3];
        const float lvv[16] = {l0.x, l0.y, l0.z, l0.w, l1.x, l1.y, l1.z, l1.w,
                               l2.x, l2.y, l2.z, l2.w, l3.x, l3.y, l3.z, l3.w};
        const uint4* col = reinterpret_cast<const uint4*>(K8 + (size_t)r0 * NR) + g;
#pragma unroll
        for (int r = 0; r < 8; ++r) {
            const uint4 w = col[(size_t)r * 512];
            const unsigned wd[4] = {w.x, w.y, w.z, w.w};
#pragma unroll
            for (int d = 0; d < 4; ++d) {
                const unsigned a = wd[d];
                s[r] += ex2(fmaf((float)(a & 255u),          C8, lvv[4 * d + 0]))
                      + ex2(fmaf((float)((a >> 8) & 255u),   C8, lvv[4 * d + 1]))
                      + ex2(fmaf((float)((a >> 16) & 255u),  C8, lvv[4 * d + 2]))
                      + ex2(fmaf((float)(a >> 24),           C8, lvv[4 * d + 3]));
            }
        }
    }
    const int lane = t & 63, w = t >> 6;
#pragma unroll
    for (int r = 0; r < 8; ++r) {
        float v = s[r];
#pragma unroll
        for (int o = 32; o; o >>= 1) v += __shfl_xor(v, o);
        if (lane == 0) red[w][r] = v;
    }
    __syncthreads();
    if (t < 8) {
        const float stot = (red[0][t] + red[1][t]) + (red[2][t] + red[3][t]);
        log_u[r0 + t] = LOG_AB2 - __log2f(stot) + off2;
    }
}

// ---------------- Sinkhorn column pass: partial sums over 32-row chunks ----------------
__global__ __launch_bounds__(256) void sink_colp_k(const unsigned char* __restrict__ K8,
                                                   const float* __restrict__ log_u,
                                                   float* __restrict__ ps) {
    const int t  = threadIdx.x;
    const int cg = blockIdx.x * 256 + t;  // uint4 group: cols 16cg..16cg+15
    const int rc = blockIdx.y;            // row chunk, 0..255 (32 rows each)
    const uint4* base = reinterpret_cast<const uint4*>(K8) + (size_t)rc * 32 * 512 + cg;
    const float* lu = log_u + rc * 32;
    float s16[16];
#pragma unroll
    for (int e = 0; e < 16; ++e) s16[e] = 0.f;
#pragma unroll 4
    for (int r = 0; r < 32; ++r) {
        const uint4 w = base[(size_t)r * 512];
        const float lur = lu[r];
        const unsigned wd[4] = {w.x, w.y, w.z, w.w};
#pragma unroll
        for (int d = 0; d < 4; ++d) {
            const unsigned a = wd[d];
            s16[4 * d + 0] += ex2(fmaf((float)(a & 255u),         C8, lur));
            s16[4 * d + 1] += ex2(fmaf((float)((a >> 8) & 255u),  C8, lur));
            s16[4 * d + 2] += ex2(fmaf((float)((a >> 16) & 255u), C8, lur));
            s16[4 * d + 3] += ex2(fmaf((float)(a >> 24),          C8, lur));
        }
    }
    float4* pv = reinterpret_cast<float4*>(ps + (size_t)rc * NR + cg * 16);
#pragma unroll
    for (int d = 0; d < 4; ++d)
        pv[d] = {s16[4 * d + 0], s16[4 * d + 1], s16[4 * d + 2], s16[4 * d + 3]};
}

// combine: 128 blocks x (4 groups x 64 lanes); 256 chunks
__global__ __launch_bounds__(256) void sink_combine_k(const float* __restrict__ ps,
                                                      float* __restrict__ log_v,
                                                      const unsigned* __restrict__ scal_u) {
    __shared__ float red[4][64];
    const int lane = threadIdx.x & 63;
    const int grp  = threadIdx.x >> 6;
    const int col  = blockIdx.x * 64 + lane;
    float s = 0.f;
#pragma unroll 8
    for (int c = grp * 64; c < grp * 64 + 64; ++c) s += ps[(size_t)c * NR + col];
    red[grp][lane] = s;
    __syncthreads();
    if (grp == 0) {
        const float stot = (red[0][lane] + red[1][lane]) + (red[2][lane] + red[3][lane]);
        const float off2 = -__uint_as_float(scal_u[0]) * INV_EPS_L2E;
        log_v[col] = LOG_AB2 - __log2f(stot) + off2;
    }
}

// ---------------- final sum(Gamma * Kxy); S accumulates Gamma*q, scaled by DQK8 at the end ----------------
__global__ __launch_bounds__(256) void gamma_sum_k(const unsigned char* __restrict__ K8,
                                                   const float* __restrict__ log_u,
                                                   const float* __restrict__ log_v,
                                                   const unsigned* __restrict__ scal_u,
                                                   double* __restrict__ S) {
    const int t  = threadIdx.x;
    const int cg = blockIdx.x * 256 + t;  // uint4 group: cols 16cg..16cg+15
    const int rc = blockIdx.y;            // 0..255, 32 rows each
    const float off2 = -__uint_as_float(scal_u[0]) * INV_EPS_L2E;
    float lvp[16];
#pragma unroll
    for (int e = 0; e < 16; ++e) lvp[e] = log_v[cg * 16 + e] - off2;
    const uint4* base = reinterpret_cast<const uint4*>(K8) + (size_t)rc * 32 * 512 + cg;
    const float* lu = log_u + rc * 32;
    double acc = 0.0;
#pragma unroll 4
    for (int r = 0; r < 32; ++r) {
        const uint4 w = base[(size_t)r * 512];
        const float lur = lu[r];
        const unsigned wd[4] = {w.x, w.y, w.z, w.w};
        float rs = 0.f;
#pragma unroll
        for (int d = 0; d < 4; ++d) {
            const unsigned a = wd[d];
            const float q0 = (float)(a & 255u);
            const float q1 = (float)((a >> 8) & 255u);
            const float q2 = (float)((a >> 16) & 255u);
            const float q3 = (float)(a >> 24);
            rs = fmaf(ex2(fmaf(q0, C8, lur + lvp[4 * d + 0])), q0, rs);
            rs = fmaf(ex2(fmaf(q1, C8, lur + lvp[4 * d + 1])), q1, rs);
            rs = fmaf(ex2(fmaf(q2, C8, lur + lvp[4 * d + 2])), q2, rs);
            rs = fmaf(ex2(fmaf(q3, C8, lur + lvp[4 * d + 3])), q3, rs);
        }
        acc += (double)rs;
    }
#pragma unroll
    for (int o = 32; o; o >>= 1) acc += __shfl_xor(acc, o);
    if ((t & 63) == 0) atomicAdd(S, acc);
}

__global__ void finalize_k(const double* __restrict__ scal, float* __restrict__ out) {
    const double inv = 1.0 / (8192.0 * 8192.0);
    out[0] = (float)(scal[1] * inv + scal[2] * inv - 2.0 * (double)DQK8 * scal[3]);
}

extern "C" void kernel_launch(void* const* d_in, const int* in_sizes, int n_in,
                              void* d_out, int out_size, void* d_ws, size_t ws_size,
                              hipStream_t stream) {
    const float* X = (const float*)d_in[0];
    const float* Y = (const float*)d_in[1];

    // ---- workspace layout ----
    char* ws = (char*)d_ws;
    unsigned char* K8 = (unsigned char*)ws;               // 67108864 B
    float* nx    = (float*)(ws + 67108864);               // 32 KB each
    float* ny    = nx + NR;
    float* log_u = ny + NR;
    float* log_v = log_u + NR;
    char*  scal  = (char*)(log_v + NR);                   // 512 B
    unsigned* scal_u = (unsigned*)scal;
    double*   scal_d = (double*)scal;                     // [1]=kxx, [2]=kyy, [3]=S
    float* ps = (float*)(scal + 512);                     // 256*8192*4 = 8 MB
    const size_t needed = 67108864 + 4 * (size_t)NR * 4 + 512 + 256 * (size_t)NR * 4;
    if (ws_size < needed) return;  // clean absmax failure instead of a GPU fault

    hipMemsetAsync(scal, 0, 512, stream);  // kmax=0 bits, sums=0

    rownorm_k<<<NR / 4, 256, 0, stream>>>(X, nx);
    rownorm_k<<<NR / 4, 256, 0, stream>>>(Y, ny);

    gemm_rbf_k<0><<<dim3(64, 64), 256, 0, stream>>>(X, Y, nx, ny, K8, scal_u, scal_d);
    gemm_rbf_k<1><<<dim3(2080, 2), 256, 0, stream>>>(X, Y, nx, ny, nullptr, scal_u, scal_d);

    init_lv_k<<<NR / 256, 256, 0, stream>>>(log_v, scal_u);

    for (int it = 0; it < 30; ++it) {
        sink_row_k<<<NR / 8, 256, 0, stream>>>(K8, log_v, log_u, scal_u);
        sink_colp_k<<<dim3(2, 256), 256, 0, stream>>>(K8, log_u, ps);
        sink_combine_k<<<128, 256, 0, stream>>>(ps, log_v, scal_u);
    }

    gamma_sum_k<<<dim3(2, 256), 256, 0, stream>>>(K8, log_u, log_v, scal_u, scal_d + 3);
    finalize_k<<<1, 1, 0, stream>>>(scal_d, (float*)d_out);
}

// Round 6
// 1603.130 us; speedup vs baseline: 2.9329x; 1.1029x over previous
//
#include <hip/hip_runtime.h>
#include <math.h>

#define NR 8192
#define DDIM 128

static constexpr float LOG_AB2 = -13.0f;                  // -log2(8192)
static constexpr float OFF2    = -28.853900817779268f;    // -(1.0)*20*log2e constant shift
static constexpr float C8      = 0.11315255222658537f;    // (20/255)*log2e
static constexpr float DQK8    = 1.0f / 255.0f;
// RBF scale constants in log2 domain: -log2e/(2 s^2)
static constexpr float E1 = -0.7213475204444817f;
static constexpr float E2 = -0.18033688011112043f;
static constexpr float E3 = -0.045084220027780107f;
static constexpr float E4 = -0.011271055006945027f;
static constexpr float E5 = -0.0028177637517362567f;

typedef __attribute__((ext_vector_type(8))) short  s16x8;
typedef __attribute__((ext_vector_type(4))) float  f32x4;

#if defined(__has_builtin)
#if __has_builtin(__builtin_amdgcn_exp2f)
#define EX2_IMPL(x) __builtin_amdgcn_exp2f(x)
#endif
#endif
#ifndef EX2_IMPL
extern "C" __device__ float __ocml_native_exp2_f32(float);
#define EX2_IMPL(x) __ocml_native_exp2_f32(x)
#endif
__device__ inline float ex2(float x) { return EX2_IMPL(x); }

__device__ inline unsigned short bf16rn(float f) {
    const unsigned u = __float_as_uint(f);
    return (unsigned short)((u + 0x7FFFu + ((u >> 16) & 1u)) >> 16);
}

// ---------------- f32 -> (hi, lo) bf16 planes ----------------
__global__ __launch_bounds__(256) void conv_k(const float* __restrict__ X,
                                              unsigned short* __restrict__ hi,
                                              unsigned short* __restrict__ lo) {
    const int i = blockIdx.x * 1024 + threadIdx.x * 4;
    const float4 v = *reinterpret_cast<const float4*>(&X[i]);
    const float f[4] = {v.x, v.y, v.z, v.w};
    ushort4 h, l;
    unsigned short hh[4], ll[4];
#pragma unroll
    for (int j = 0; j < 4; ++j) {
        const unsigned short a = bf16rn(f[j]);
        const float hf = __uint_as_float((unsigned)a << 16);
        hh[j] = a;
        ll[j] = bf16rn(f[j] - hf);
    }
    h.x = hh[0]; h.y = hh[1]; h.z = hh[2]; h.w = hh[3];
    l.x = ll[0]; l.y = ll[1]; l.z = ll[2]; l.w = ll[3];
    *reinterpret_cast<ushort4*>(&hi[i]) = h;
    *reinterpret_cast<ushort4*>(&lo[i]) = l;
}

// ---------------- row squared-norms ----------------
__global__ __launch_bounds__(256) void rownorm_k(const float* __restrict__ X,
                                                 float* __restrict__ nrm) {
    const int lane = threadIdx.x & 63;
    const int w    = threadIdx.x >> 6;
    const int row  = blockIdx.x * 4 + w;
    const float2 v = *reinterpret_cast<const float2*>(&X[(size_t)row * DDIM + lane * 2]);
    float s = v.x * v.x + v.y * v.y;
#pragma unroll
    for (int off = 32; off; off >>= 1) s += __shfl_xor(s, off);
    if (lane == 0) nrm[row] = s;
}

// ---------------- MFMA split-bf16 GEMM + multi-scale RBF ----------------
// C = A.B^T via 3x mfma_f32_16x16x32_bf16 (hi*hi + hi*lo + lo*hi).
// MODE 0: full 64x64 grid (X vs Y), store uint8 K.
// MODE 1: triangular 2080 x 2 grid (sel: X or Y), sum only; double off-diag blocks.
template <int MODE>
__global__ __launch_bounds__(256) void gemm_mfma_k(const unsigned short* __restrict__ XH,
                                                   const unsigned short* __restrict__ XL,
                                                   const unsigned short* __restrict__ YH,
                                                   const unsigned short* __restrict__ YL,
                                                   const float* __restrict__ nxp,
                                                   const float* __restrict__ nyp,
                                                   unsigned char* __restrict__ K8,
                                                   double* __restrict__ sums) {
    int bm, bn;
    const unsigned short *AH, *AL, *BH, *BL;
    const float *na, *nb;
    if (MODE == 0) {
        bm = blockIdx.x; bn = blockIdx.y;
        AH = XH; AL = XL; BH = YH; BL = YL; na = nxp; nb = nyp;
    } else {
        const int lin = blockIdx.x;  // 0..2079 triangular (bm<=bn)
        int i = (int)((129.0f - sqrtf(16641.0f - 8.0f * (float)lin)) * 0.5f);
        while (i * 64 - i * (i - 1) / 2 > lin) --i;
        while ((i + 1) * 64 - (i + 1) * i / 2 <= lin) ++i;
        bm = i;
        bn = i + (lin - (i * 64 - i * (i - 1) / 2));
        const int sel = blockIdx.y;
        AH = BH = sel ? YH : XH;
        AL = BL = sel ? YL : XL;
        na = nb = sel ? nyp : nxp;
    }
    // padded LDS: 40 ushort (80 B) per row -> <=2-way bank aliasing on ds_read_b128
    __shared__ unsigned short AsH[128 * 40], AsL[128 * 40], BsH[128 * 40], BsL[128 * 40];

    const int t    = threadIdx.x;
    const int lane = t & 63;
    const int w    = t >> 6;
    const int wr   = w >> 1, wc = w & 1;      // 2x2 wave grid, 64x64 sub-tile each
    const int l15  = lane & 15, lg = lane >> 4;

    f32x4 acc[4][4];
#pragma unroll
    for (int mi = 0; mi < 4; ++mi)
#pragma unroll
        for (int ni = 0; ni < 4; ++ni) acc[mi][ni] = (f32x4){0.f, 0.f, 0.f, 0.f};

    const unsigned short* gAH = AH + (size_t)(bm * 128) * DDIM;
    const unsigned short* gAL = AL + (size_t)(bm * 128) * DDIM;
    const unsigned short* gBH = BH + (size_t)(bn * 128) * DDIM;
    const unsigned short* gBL = BL + (size_t)(bn * 128) * DDIM;

    for (int kc = 0; kc < 4; ++kc) {
        const int k0 = kc * 32;
        __syncthreads();
#pragma unroll
        for (int q = 0; q < 2; ++q) {
            const int idx = t + q * 256;        // 0..511
            const int row = idx >> 2, seg = idx & 3;
            const int go = row * DDIM + k0 + seg * 8;
            const int so = row * 40 + seg * 8;
            *reinterpret_cast<uint4*>(&AsH[so]) = *reinterpret_cast<const uint4*>(&gAH[go]);
            *reinterpret_cast<uint4*>(&AsL[so]) = *reinterpret_cast<const uint4*>(&gAL[go]);
            *reinterpret_cast<uint4*>(&BsH[so]) = *reinterpret_cast<const uint4*>(&gBH[go]);
            *reinterpret_cast<uint4*>(&BsL[so]) = *reinterpret_cast<const uint4*>(&gBL[go]);
        }
        __syncthreads();

        s16x8 bh[4], bl[4];
#pragma unroll
        for (int ni = 0; ni < 4; ++ni) {
            const int off = (wc * 64 + ni * 16 + l15) * 40 + lg * 8;
            bh[ni] = *reinterpret_cast<const s16x8*>(&BsH[off]);
            bl[ni] = *reinterpret_cast<const s16x8*>(&BsL[off]);
        }
#pragma unroll
        for (int mi = 0; mi < 4; ++mi) {
            const int off = (wr * 64 + mi * 16 + l15) * 40 + lg * 8;
            const s16x8 ah = *reinterpret_cast<const s16x8*>(&AsH[off]);
            const s16x8 al = *reinterpret_cast<const s16x8*>(&AsL[off]);
#pragma unroll
            for (int ni = 0; ni < 4; ++ni) {
                acc[mi][ni] = __builtin_amdgcn_mfma_f32_16x16x32_bf16(ah, bh[ni], acc[mi][ni], 0, 0, 0);
                acc[mi][ni] = __builtin_amdgcn_mfma_f32_16x16x32_bf16(ah, bl[ni], acc[mi][ni], 0, 0, 0);
                acc[mi][ni] = __builtin_amdgcn_mfma_f32_16x16x32_bf16(al, bh[ni], acc[mi][ni], 0, 0, 0);
            }
        }
    }

    // epilogue; C/D layout: col = lane&15, row = (lane>>4)*4 + j  [HW-verified]
    const int mBase = bm * 128 + wr * 64;
    const int nBase = bn * 128 + wc * 64;
    float nbv[4];
#pragma unroll
    for (int ni = 0; ni < 4; ++ni) nbv[ni] = nb[nBase + ni * 16 + l15];

    if (MODE == 0) {
#pragma unroll
        for (int mi = 0; mi < 4; ++mi) {
#pragma unroll
            for (int j = 0; j < 4; ++j) {
                const int m = mBase + mi * 16 + lg * 4 + j;
                const float nav = na[m];
                unsigned char* krow = &K8[(size_t)m * NR + nBase + l15];
#pragma unroll
                for (int ni = 0; ni < 4; ++ni) {
                    float d2 = fmaf(-2.f, acc[mi][ni][j], nav + nbv[ni]);
                    d2 = fmaxf(d2, 0.f);
                    const float kv = 0.2f * (ex2(d2 * E1) + ex2(d2 * E2) + ex2(d2 * E3) +
                                             ex2(d2 * E4) + ex2(d2 * E5));
                    krow[ni * 16] = (unsigned char)__float2uint_rn(kv * 255.f);
                }
            }
        }
    } else {
        double lsum = 0.0;
#pragma unroll
        for (int mi = 0; mi < 4; ++mi) {
#pragma unroll
            for (int j = 0; j < 4; ++j) {
                const int m = mBase + mi * 16 + lg * 4 + j;
                const float nav = na[m];
                float rs = 0.f;
#pragma unroll
                for (int ni = 0; ni < 4; ++ni) {
                    float d2 = fmaf(-2.f, acc[mi][ni][j], nav + nbv[ni]);
                    d2 = fmaxf(d2, 0.f);
                    rs += 0.2f * (ex2(d2 * E1) + ex2(d2 * E2) + ex2(d2 * E3) +
                                  ex2(d2 * E4) + ex2(d2 * E5));
                }
                lsum += (double)rs;
            }
        }
        if (bn > bm) lsum *= 2.0;
#pragma unroll
        for (int o = 32; o; o >>= 1) lsum += __shfl_xor(lsum, o);
        if (lane == 0) atomicAdd(&sums[1 + blockIdx.y], lsum);
    }
}

// log_v initial state: exact log_v=0 -> stored = OFF2
__global__ __launch_bounds__(256) void init_lv_k(float* __restrict__ log_v) {
    log_v[blockIdx.x * 256 + threadIdx.x] = OFF2;
}

// ---------------- Sinkhorn row pass: 8 rows/block ----------------
__global__ __launch_bounds__(256) void sink_row_k(const unsigned char* __restrict__ K8,
                                                  const float* __restrict__ log_v,
                                                  float* __restrict__ log_u) {
    __shared__ float red[4][8];
    const int t  = threadIdx.x;
    const int r0 = blockIdx.x * 8;
    const float4* Lv4 = reinterpret_cast<const float4*>(log_v);
    float s[8];
#pragma unroll
    for (int r = 0; r < 8; ++r) s[r] = 0.f;
#pragma unroll
    for (int p = 0; p < 2; ++p) {
        const int g = t + p * 256;  // uint4 group: cols 16g..16g+15
        const float4 l0 = Lv4[4 * g + 0];
        const float4 l1 = Lv4[4 * g + 1];
        const float4 l2 = Lv4[4 * g + 2];
        const float4 l3 = Lv4[4 * g + 3];
        const float lvv[16] = {l0.x, l0.y, l0.z, l0.w, l1.x, l1.y, l1.z, l1.w,
                               l2.x, l2.y, l2.z, l2.w, l3.x, l3.y, l3.z, l3.w};
        const uint4* col = reinterpret_cast<const uint4*>(K8 + (size_t)r0 * NR) + g;
#pragma unroll
        for (int r = 0; r < 8; ++r) {
            const uint4 w = col[(size_t)r * 512];
            const unsigned wd[4] = {w.x, w.y, w.z, w.w};
#pragma unroll
            for (int d = 0; d < 4; ++d) {
                const unsigned a = wd[d];
                s[r] += ex2(fmaf((float)(a & 255u),          C8, lvv[4 * d + 0]))
                      + ex2(fmaf((float)((a >> 8) & 255u),   C8, lvv[4 * d + 1]))
                      + ex2(fmaf((float)((a >> 16) & 255u),  C8, lvv[4 * d + 2]))
                      + ex2(fmaf((float)(a >> 24),           C8, lvv[4 * d + 3]));
            }
        }
    }
    const int lane = t & 63, w = t >> 6;
#pragma unroll
    for (int r = 0; r < 8; ++r) {
        float v = s[r];
#pragma unroll
        for (int o = 32; o; o >>= 1) v += __shfl_xor(v, o);
        if (lane == 0) red[w][r] = v;
    }
    __syncthreads();
    if (t < 8) {
        const float stot = (red[0][t] + red[1][t]) + (red[2][t] + red[3][t]);
        log_u[r0 + t] = LOG_AB2 - __log2f(stot) + OFF2;
    }
}

// ---------------- Sinkhorn column pass: partial sums over 32-row chunks ----------------
__global__ __launch_bounds__(256) void sink_colp_k(const unsigned char* __restrict__ K8,
                                                   const float* __restrict__ log_u,
                                                   float* __restrict__ ps) {
    const int t  = threadIdx.x;
    const int cg = blockIdx.x * 256 + t;  // uint4 group: cols 16cg..16cg+15
    const int rc = blockIdx.y;            // row chunk, 0..255 (32 rows each)
    const uint4* base = reinterpret_cast<const uint4*>(K8) + (size_t)rc * 32 * 512 + cg;
    const float* lu = log_u + rc * 32;
    float s16[16];
#pragma unroll
    for (int e = 0; e < 16; ++e) s16[e] = 0.f;
#pragma unroll 4
    for (int r = 0; r < 32; ++r) {
        const uint4 w = base[(size_t)r * 512];
        const float lur = lu[r];
        const unsigned wd[4] = {w.x, w.y, w.z, w.w};
#pragma unroll
        for (int d = 0; d < 4; ++d) {
            const unsigned a = wd[d];
            s16[4 * d + 0] += ex2(fmaf((float)(a & 255u),         C8, lur));
            s16[4 * d + 1] += ex2(fmaf((float)((a >> 8) & 255u),  C8, lur));
            s16[4 * d + 2] += ex2(fmaf((float)((a >> 16) & 255u), C8, lur));
            s16[4 * d + 3] += ex2(fmaf((float)(a >> 24),          C8, lur));
        }
    }
    float4* pv = reinterpret_cast<float4*>(ps + (size_t)rc * NR + cg * 16);
#pragma unroll
    for (int d = 0; d < 4; ++d)
        pv[d] = {s16[4 * d + 0], s16[4 * d + 1], s16[4 * d + 2], s16[4 * d + 3]};
}

// combine: 128 blocks x (4 groups x 64 lanes); 256 chunks
__global__ __launch_bounds__(256) void sink_combine_k(const float* __restrict__ ps,
                                                      float* __restrict__ log_v) {
    __shared__ float red[4][64];
    const int lane = threadIdx.x & 63;
    const int grp  = threadIdx.x >> 6;
    const int col  = blockIdx.x * 64 + lane;
    float s = 0.f;
#pragma unroll 8
    for (int c = grp * 64; c < grp * 64 + 64; ++c) s += ps[(size_t)c * NR + col];
    red[grp][lane] = s;
    __syncthreads();
    if (grp == 0) {
        const float stot = (red[0][lane] + red[1][lane]) + (red[2][lane] + red[3][lane]);
        log_v[col] = LOG_AB2 - __log2f(stot) + OFF2;
    }
}

// ---------------- final sum(Gamma * Kxy); scaled by DQK8 in finalize ----------------
__global__ __launch_bounds__(256) void gamma_sum_k(const unsigned char* __restrict__ K8,
                                                   const float* __restrict__ log_u,
                                                   const float* __restrict__ log_v,
                                                   double* __restrict__ S) {
    const int t  = threadIdx.x;
    const int cg = blockIdx.x * 256 + t;  // uint4 group: cols 16cg..16cg+15
    const int rc = blockIdx.y;            // 0..255, 32 rows each
    float lvp[16];
#pragma unroll
    for (int e = 0; e < 16; ++e) lvp[e] = log_v[cg * 16 + e] - OFF2;
    const uint4* base = reinterpret_cast<const uint4*>(K8) + (size_t)rc * 32 * 512 + cg;
    const float* lu = log_u + rc * 32;
    double acc = 0.0;
#pragma unroll 4
    for (int r = 0; r < 32; ++r) {
        const uint4 w = base[(size_t)r * 512];
        const float lur = lu[r];
        const unsigned wd[4] = {w.x, w.y, w.z, w.w};
        float rs = 0.f;
#pragma unroll
        for (int d = 0; d < 4; ++d) {
            const unsigned a = wd[d];
            const float q0 = (float)(a & 255u);
            const float q1 = (float)((a >> 8) & 255u);
            const float q2 = (float)((a >> 16) & 255u);
            const float q3 = (float)(a >> 24);
            rs = fmaf(ex2(fmaf(q0, C8, lur + lvp[4 * d + 0])), q0, rs);
            rs = fmaf(ex2(fmaf(q1, C8, lur + lvp[4 * d + 1])), q1, rs);
            rs = fmaf(ex2(fmaf(q2, C8, lur + lvp[4 * d + 2])), q2, rs);
            rs = fmaf(ex2(fmaf(q3, C8, lur + lvp[4 * d + 3])), q3, rs);
        }
        acc += (double)rs;
    }
#pragma unroll
    for (int o = 32; o; o >>= 1) acc += __shfl_xor(acc, o);
    if ((t & 63) == 0) atomicAdd(S, acc);
}

__global__ void finalize_k(const double* __restrict__ scal, float* __restrict__ out) {
    const double inv = 1.0 / (8192.0 * 8192.0);
    out[0] = (float)(scal[1] * inv + scal[2] * inv - 2.0 * (double)DQK8 * scal[3]);
}

extern "C" void kernel_launch(void* const* d_in, const int* in_sizes, int n_in,
                              void* d_out, int out_size, void* d_ws, size_t ws_size,
                              hipStream_t stream) {
    const float* X = (const float*)d_in[0];
    const float* Y = (const float*)d_in[1];

    // ---- workspace layout ----
    char* ws = (char*)d_ws;
    unsigned char* K8 = (unsigned char*)ws;               // 67108864 B
    float* nx    = (float*)(ws + 67108864);               // 32 KB each
    float* ny    = nx + NR;
    float* log_u = ny + NR;
    float* log_v = log_u + NR;
    char*  scal  = (char*)(log_v + NR);                   // 512 B
    double* scal_d = (double*)scal;                       // [1]=kxx, [2]=kyy, [3]=S
    float* ps = (float*)(scal + 512);                     // 8 MB
    unsigned short* XH = (unsigned short*)(ws + 75629056);  // 2 MB each
    unsigned short* XL = XH + NR * DDIM;
    unsigned short* YH = XL + NR * DDIM;
    unsigned short* YL = YH + NR * DDIM;
    const size_t needed = 75629056 + 4 * (size_t)NR * DDIM * 2;
    if (ws_size < needed) return;  // clean absmax failure instead of a GPU fault

    hipMemsetAsync(scal, 0, 512, stream);  // sums = 0

    conv_k<<<NR * DDIM / 1024, 256, 0, stream>>>(X, XH, XL);
    conv_k<<<NR * DDIM / 1024, 256, 0, stream>>>(Y, YH, YL);
    rownorm_k<<<NR / 4, 256, 0, stream>>>(X, nx);
    rownorm_k<<<NR / 4, 256, 0, stream>>>(Y, ny);

    gemm_mfma_k<0><<<dim3(64, 64), 256, 0, stream>>>(XH, XL, YH, YL, nx, ny, K8, scal_d);
    gemm_mfma_k<1><<<dim3(2080, 2), 256, 0, stream>>>(XH, XL, YH, YL, nx, ny, nullptr, scal_d);

    init_lv_k<<<NR / 256, 256, 0, stream>>>(log_v);

    for (int it = 0; it < 30; ++it) {
        sink_row_k<<<NR / 8, 256, 0, stream>>>(K8, log_v, log_u);
        sink_colp_k<<<dim3(2, 256), 256, 0, stream>>>(K8, log_u, ps);
        sink_combine_k<<<128, 256, 0, stream>>>(ps, log_v);
    }

    gamma_sum_k<<<dim3(2, 256), 256, 0, stream>>>(K8, log_u, log_v, scal_d + 3);
    finalize_k<<<1, 1, 0, stream>>>(scal_d, (float*)d_out);
}